// Round 10
// baseline (3844.881 us; speedup 1.0000x reference)
//
#include <hip/hip_runtime.h>

typedef _Float16 f16;
typedef _Float16 f16x8 __attribute__((ext_vector_type(8)));
typedef float f32x4 __attribute__((ext_vector_type(4)));
typedef unsigned long long u64;

#define B_ 64
#define S_ 1024
#define E_ 256
#define H_ 512
#define NG 1536
#define V_ 50257
#define HS_LD 544       // h LDS row stride (f16)
#define XLS_LD 264      // x LDS row stride (f16)
#define DSLOT 32        // deep h0 ring slots
#define LEAD 24         // L0 anti-overrun slack (< DSLOT-4)

__device__ __forceinline__ float sigm(float x) { return 1.f / (1.f + __expf(-x)); }

#define ALOAD(p) __hip_atomic_load((p), __ATOMIC_RELAXED, __HIP_MEMORY_SCOPE_AGENT)
#define ASTORE(p, v) __hip_atomic_store((p), (v), __ATOMIC_RELAXED, __HIP_MEMORY_SCOPE_AGENT)

// ------------- pack [gate_w slice ; gi_or_gh_w] into fp16 [1536][KK] -------------
__global__ __launch_bounds__(256) void k_packW(const float* __restrict__ gw, int ld, int off,
        const float* __restrict__ g2, f16* __restrict__ W, int KK) {
    int idx = blockIdx.x * 256 + threadIdx.x;
    int per = KK >> 2;
    if (idx >= NG * per) return;
    int row = idx / per;
    int c4 = (idx % per) << 2;
    const float* src = (row < 1024) ? gw + (size_t)row * ld + off + c4
                                    : g2 + (size_t)(row - 1024) * KK + c4;
    float4 v = *reinterpret_cast<const float4*>(src);
    union { f16 h[4]; u64 u; } w;
    w.h[0] = (f16)v.x; w.h[1] = (f16)v.y; w.h[2] = (f16)v.z; w.h[3] = (f16)v.w;
    *reinterpret_cast<u64*>(W + (size_t)row * KK + c4) = w.u;
}

// ------------------------- emb fp32 -> fp16 (one-time) -------------------------
__global__ __launch_bounds__(256) void k_embconv(const float* __restrict__ emb,
        f16* __restrict__ out) {
    long long i = (long long)blockIdx.x * 256 + threadIdx.x;
    if (i >= (long long)V_ * E_ / 4) return;
    float4 v = reinterpret_cast<const float4*>(emb)[i];
    union { f16 h[4]; u64 u; } w;
    w.h[0] = (f16)v.x; w.h[1] = (f16)v.y; w.h[2] = (f16)v.z; w.h[3] = (f16)v.w;
    reinterpret_cast<u64*>(out)[i] = w.u;
}

// ------------------ fused persistent 2-layer GRU, tag-granule sync ------------------
// 256 WGs x 256 thr (1/CU). c=blk&7 (cluster of 8 batches), l=(blk>>3)&1 (layer),
// gg=blk>>4 (0..15): WG owns 32 outputs of its layer. Wave = 2 MFMA tiles; A-rows per
// output {r, z, n_h, n_x} fold the h- and x-matmuls into ONE C tile (no Z GEMMs).
// Exchange = R9's proven tag-in-data granules (u64 = tag<<32 | 2xf16, relaxed agent
// atomics; consumer retries until tag matches; no flags/drains/RMW).
// L0 publishes h0(s+1) into its own 4-ring AND a 32-slot deep ring; L1 (trailing by 1)
// reads h0(s+1) from the deep ring (tag fresh in steady state -> no wait) + h1(s) from
// its own 4-ring. L0 paces itself via a LEAD-step anti-overrun probe on L1's ring.
__global__ __launch_bounds__(256, 1) void k_fused(
    const f16* __restrict__ Wx0p, const f16* __restrict__ Wh0p,
    const f16* __restrict__ Wx1p, const f16* __restrict__ Wh1p,
    const float* __restrict__ gb0, const float* __restrict__ gib0, const float* __restrict__ ghb0,
    const float* __restrict__ gb1, const float* __restrict__ gib1, const float* __restrict__ ghb1,
    const int* __restrict__ tok, const f16* __restrict__ embh,
    u64* ring0, u64* ring1, u64* d0r, f16* __restrict__ h1out)
{
    __shared__ __align__(16) f16 HSa[8][HS_LD];      // h-state (h0 for L0 / h1 for L1)
    __shared__ __align__(16) f16 HSb[8][HS_LD];      // L1: h0(s+1) x-input
    __shared__ __align__(16) f16 xls[2][8][XLS_LD];  // L0: x(t) double buffer
    __shared__ __align__(16) f16 hx[8][40];          // gathered h_next
    const int blk = blockIdx.x;
    const int c = blk & 7;
    const int l = (blk >> 3) & 1;
    const int gg = blk >> 4;                         // 0..15
    const int i0 = gg << 5;
    const int tid = threadIdx.x;
    const int w = tid >> 6, lane = tid & 63;
    const int colb = lane & 15, bq = lane & 7, j4 = lane >> 4;
    const int rrow = lane & 15;
    const int ol = rrow >> 2, gate = rrow & 3;       // A-row = ol*4 + gate

    const f16* Whp = l ? Wh1p : Wh0p;
    const f16* Wxp = l ? Wx1p : Wx0p;
    const int KXn = l ? 16 : 8;                      // x-side K-steps (K=512 / K=256)
    const int KXw = l ? 512 : 256;

    // ---- weights into registers/AGPRs (constant all 1024 steps) ----
    // Wh rows per output: gate 0->r, 1->z, 2->n_h, 3->zero
    // Wx rows per output: gate 0->r, 1->z, 2->zero, 3->n_x (row 1024+out)
    f16x8 wh[2][16], wx[2][16];
    #pragma unroll
    for (int tl = 0; tl < 2; ++tl) {
        const int out = i0 + (w << 3) + (tl << 2) + ol;
        const int rH = (gate < 3) ? (gate * 512 + out) : -1;
        const int rX = (gate < 2) ? (gate * 512 + out) : (gate == 3 ? 1024 + out : -1);
        #pragma unroll
        for (int t = 0; t < 16; ++t) {
            f16x8 v{};
            if (rH >= 0) v = *(const f16x8*)(Whp + (size_t)rH * 512 + (t << 5) + (j4 << 3));
            wh[tl][t] = v;
        }
        #pragma unroll
        for (int t = 0; t < 16; ++t) {
            f16x8 v{};
            if (rX >= 0 && t < KXn)
                v = *(const f16x8*)(Wxp + (size_t)rX * KXw + (t << 5) + (j4 << 3));
            wx[tl][t] = v;
        }
    }
    const float* gb  = l ? gb1 : gb0;
    const float* gib = l ? gib1 : gib0;
    const float* ghb = l ? ghb1 : ghb0;
    const int outA = i0 + (w << 3) + j4, outB = outA + 4;
    const float bRA = gb[outA], bZA = gb[512 + outA], bIA = gib[outA], bHA = ghb[outA];
    const float bRB = gb[outB], bZB = gb[512 + outB], bIB = gib[outB], bHB = ghb[outB];

    u64* myring = l ? ring1 : ring0;                 // [4][8][2048]

    if (l == 0) {
        // prologue: stage x(0)
        if (tid < 128) {
            int sb = tid >> 4, seg = tid & 15;
            int tk = tok[((c << 3) + sb) * S_];
            const f16* ep = embh + (size_t)tk * E_ + (seg << 4);
            *(f16x8*)&xls[0][sb][seg << 4]       = *(const f16x8*)ep;
            *(f16x8*)&xls[0][sb][(seg << 4) + 8] = *(const f16x8*)(ep + 8);
        }
        __syncthreads();
        for (int s = 0; s < S_; ++s) {
            const int cur = s & 1;
            // x(s+1) prefetch into regs (flag-independent)
            f16x8 e0{}, e1{};
            const bool havex = (tid < 128) && (s + 1 < S_);
            if (havex) {
                int tk = tok[((c << 3) + (tid >> 4)) * S_ + s + 1];
                const f16* ep = embh + (size_t)tk * E_ + ((tid & 15) << 4);
                e0 = *(const f16x8*)ep; e1 = *(const f16x8*)(ep + 8);
            }
            // anti-overrun: L1 must have published tag >= s-LEAD (steady state: instant)
            if (tid == 0 && s > LEAD) {
                const u64* pr = ring1 + ((size_t)((s - LEAD) & 3) * 8 + c) * 2048;
                while ((int)(unsigned)(ALOAD(pr) >> 32) < s - LEAD) {}
            }
            // stage h0(s): 8 tagged granules/thread, retry until tag==s
            {
                const u64* src = myring + ((size_t)(s & 3) * 8 + c) * 2048;
                u64 g[8];
                #pragma unroll
                for (int i = 0; i < 8; ++i) g[i] = ALOAD(src + (i << 8) + tid);
                #pragma unroll
                for (int i = 0; i < 8; ++i) {
                    while ((unsigned)(g[i] >> 32) != (unsigned)s)
                        g[i] = ALOAD(src + (i << 8) + tid);
                    *reinterpret_cast<unsigned*>(
                        &HSa[i][((tid >> 4) << 5) + ((tid & 15) << 1)]) = (unsigned)g[i];
                }
            }
            __syncthreads();
            // MFMA: Wh0 @ h0(s) (16 t) + Wx0 @ x(s) (8 t), 2 tiles, shared B
            f32x4 p00{}, p01{}, p10{}, p11{};
            #pragma unroll
            for (int t = 0; t < 16; ++t) {
                f16x8 bf = *(const f16x8*)&HSa[bq][(t << 5) + (j4 << 3)];
                if (t & 1) { p01 = __builtin_amdgcn_mfma_f32_16x16x32_f16(wh[0][t], bf, p01, 0, 0, 0);
                             p11 = __builtin_amdgcn_mfma_f32_16x16x32_f16(wh[1][t], bf, p11, 0, 0, 0); }
                else       { p00 = __builtin_amdgcn_mfma_f32_16x16x32_f16(wh[0][t], bf, p00, 0, 0, 0);
                             p10 = __builtin_amdgcn_mfma_f32_16x16x32_f16(wh[1][t], bf, p10, 0, 0, 0); }
            }
            #pragma unroll
            for (int t = 0; t < 8; ++t) {
                f16x8 bf = *(const f16x8*)&xls[cur][bq][(t << 5) + (j4 << 3)];
                if (t & 1) { p01 = __builtin_amdgcn_mfma_f32_16x16x32_f16(wx[0][t], bf, p01, 0, 0, 0);
                             p11 = __builtin_amdgcn_mfma_f32_16x16x32_f16(wx[1][t], bf, p11, 0, 0, 0); }
                else       { p00 = __builtin_amdgcn_mfma_f32_16x16x32_f16(wx[0][t], bf, p00, 0, 0, 0);
                             p10 = __builtin_amdgcn_mfma_f32_16x16x32_f16(wx[1][t], bf, p10, 0, 0, 0); }
            }
            f32x4 dA = p00 + p01, dB = p10 + p11;    // rows {r, z, n_h, n_x}
            if (colb < 8) {
                float rA = sigm(dA[0] + bRA), zA = sigm(dA[1] + bZA);
                float nA = tanhf(dA[3] + bIA + rA * (dA[2] + bHA));
                float hA = (float)HSa[bq][outA];
                float rB = sigm(dB[0] + bRB), zB = sigm(dB[1] + bZB);
                float nB = tanhf(dB[3] + bIB + rB * (dB[2] + bHB));
                float hB = (float)HSa[bq][outB];
                hx[bq][(w << 3) + j4]     = (f16)((1.f - zA) * nA + zA * hA);
                hx[bq][(w << 3) + 4 + j4] = (f16)((1.f - zB) * nB + zB * hB);
            }
            if (havex) {
                int sb = tid >> 4, seg = tid & 15;
                *(f16x8*)&xls[cur ^ 1][sb][seg << 4]       = e0;
                *(f16x8*)&xls[cur ^ 1][sb][(seg << 4) + 8] = e1;
            }
            __syncthreads();
            // publish h0(s+1): own 4-ring + deep ring (both tagged; no drains)
            if (tid < 128) {
                const int b = tid >> 4, d = tid & 15;
                unsigned dval = *reinterpret_cast<const unsigned*>(&hx[b][d << 1]);
                u64 gr = ((u64)(unsigned)(s + 1) << 32) | (u64)dval;
                const size_t gi = ((size_t)b << 8) + (gg << 4) + d;
                ASTORE(myring + ((size_t)((s + 1) & 3) * 8 + c) * 2048 + gi, gr);
                ASTORE(d0r + ((size_t)((s + 1) & (DSLOT - 1)) * 8 + c) * 2048 + gi, gr);
            }
        }
    } else {
        for (int s = 0; s < S_; ++s) {
            // stage h1(s) [own ring, tag s] + h0(s+1) [deep ring, tag s+1]
            {
                const u64* s1 = myring + ((size_t)(s & 3) * 8 + c) * 2048;
                const u64* s0 = d0r + ((size_t)((s + 1) & (DSLOT - 1)) * 8 + c) * 2048;
                u64 g1[8], g0[8];
                #pragma unroll
                for (int i = 0; i < 8; ++i) g1[i] = ALOAD(s1 + (i << 8) + tid);
                #pragma unroll
                for (int i = 0; i < 8; ++i) g0[i] = ALOAD(s0 + (i << 8) + tid);
                #pragma unroll
                for (int i = 0; i < 8; ++i) {
                    while ((unsigned)(g1[i] >> 32) != (unsigned)s)
                        g1[i] = ALOAD(s1 + (i << 8) + tid);
                    *reinterpret_cast<unsigned*>(
                        &HSa[i][((tid >> 4) << 5) + ((tid & 15) << 1)]) = (unsigned)g1[i];
                }
                #pragma unroll
                for (int i = 0; i < 8; ++i) {
                    while ((unsigned)(g0[i] >> 32) != (unsigned)(s + 1))
                        g0[i] = ALOAD(s0 + (i << 8) + tid);
                    *reinterpret_cast<unsigned*>(
                        &HSb[i][((tid >> 4) << 5) + ((tid & 15) << 1)]) = (unsigned)g0[i];
                }
            }
            __syncthreads();
            // MFMA: Wh1 @ h1(s) + Wx1 @ h0(s+1), both K=512, 2 tiles, shared B
            f32x4 p00{}, p01{}, p10{}, p11{};
            #pragma unroll
            for (int t = 0; t < 16; ++t) {
                f16x8 bf = *(const f16x8*)&HSa[bq][(t << 5) + (j4 << 3)];
                if (t & 1) { p01 = __builtin_amdgcn_mfma_f32_16x16x32_f16(wh[0][t], bf, p01, 0, 0, 0);
                             p11 = __builtin_amdgcn_mfma_f32_16x16x32_f16(wh[1][t], bf, p11, 0, 0, 0); }
                else       { p00 = __builtin_amdgcn_mfma_f32_16x16x32_f16(wh[0][t], bf, p00, 0, 0, 0);
                             p10 = __builtin_amdgcn_mfma_f32_16x16x32_f16(wh[1][t], bf, p10, 0, 0, 0); }
            }
            #pragma unroll
            for (int t = 0; t < 16; ++t) {
                f16x8 bf = *(const f16x8*)&HSb[bq][(t << 5) + (j4 << 3)];
                if (t & 1) { p01 = __builtin_amdgcn_mfma_f32_16x16x32_f16(wx[0][t], bf, p01, 0, 0, 0);
                             p11 = __builtin_amdgcn_mfma_f32_16x16x32_f16(wx[1][t], bf, p11, 0, 0, 0); }
                else       { p00 = __builtin_amdgcn_mfma_f32_16x16x32_f16(wx[0][t], bf, p00, 0, 0, 0);
                             p10 = __builtin_amdgcn_mfma_f32_16x16x32_f16(wx[1][t], bf, p10, 0, 0, 0); }
            }
            f32x4 dA = p00 + p01, dB = p10 + p11;    // rows {r, z, n_h, n_x}
            if (colb < 8) {
                float rA = sigm(dA[0] + bRA), zA = sigm(dA[1] + bZA);
                float nA = tanhf(dA[3] + bIA + rA * (dA[2] + bHA));
                float hA = (float)HSa[bq][outA];
                float rB = sigm(dB[0] + bRB), zB = sigm(dB[1] + bZB);
                float nB = tanhf(dB[3] + bIB + rB * (dB[2] + bHB));
                float hB = (float)HSa[bq][outB];
                hx[bq][(w << 3) + j4]     = (f16)((1.f - zA) * nA + zA * hA);
                hx[bq][(w << 3) + 4 + j4] = (f16)((1.f - zB) * nB + zB * hB);
            }
            __syncthreads();
            // publish h1(s+1); final step also writes plain h1out for the head
            if (tid < 128) {
                const int b = tid >> 4, d = tid & 15;
                unsigned dval = *reinterpret_cast<const unsigned*>(&hx[b][d << 1]);
                u64 gr = ((u64)(unsigned)(s + 1) << 32) | (u64)dval;
                ASTORE(myring + ((size_t)((s + 1) & 3) * 8 + c) * 2048
                              + ((size_t)b << 8) + (gg << 4) + d, gr);
                if (s == S_ - 1)
                    *reinterpret_cast<unsigned*>(
                        &h1out[((size_t)(c << 3) + b) * H_ + i0 + (d << 1)]) = dval;
            }
        }
    }
}

// ------------------------------- final head -------------------------------
__global__ __launch_bounds__(64) void k_final(const f16* __restrict__ h,
        const float* __restrict__ fcw, const float* __restrict__ fcb,
        float* __restrict__ out) {
    int b = threadIdx.x;
    float acc = fcb[0];
    for (int k = 0; k < H_; ++k) acc += (float)h[(size_t)b * H_ + k] * fcw[k];
    out[b] = sigm(acc);
}

extern "C" void kernel_launch(void* const* d_in, const int* in_sizes, int n_in,
                              void* d_out, int out_size, void* d_ws, size_t ws_size,
                              hipStream_t stream) {
    (void)in_sizes; (void)n_in; (void)out_size; (void)ws_size;
    const int*   tokens = (const int*)d_in[0];
    const float* emb  = (const float*)d_in[1];
    const float* fc_w = (const float*)d_in[2];
    const float* fc_b = (const float*)d_in[3];
    const float* gw0  = (const float*)d_in[4];
    const float* gb0  = (const float*)d_in[5];
    const float* giw0 = (const float*)d_in[6];
    const float* gib0 = (const float*)d_in[7];
    const float* ghw0 = (const float*)d_in[8];
    const float* ghb0 = (const float*)d_in[9];
    const float* gw1  = (const float*)d_in[10];
    const float* gb1  = (const float*)d_in[11];
    const float* giw1 = (const float*)d_in[12];
    const float* gib1 = (const float*)d_in[13];
    const float* ghw1 = (const float*)d_in[14];
    const float* ghb1 = (const float*)d_in[15];

    char* base = (char*)d_ws;
    size_t off = 0;
    auto carve = [&](size_t bytes) {
        char* p = base + off;
        off = (off + bytes + 255) & ~(size_t)255;
        return p;
    };
    f16*   embh  = (f16*)carve((size_t)V_ * E_ * 2);            // ~25.7 MB
    f16*   Wx0   = (f16*)carve((size_t)NG * 256 * 2);
    f16*   Wh0   = (f16*)carve((size_t)NG * 512 * 2);
    f16*   Wx1   = (f16*)carve((size_t)NG * 512 * 2);
    f16*   Wh1   = (f16*)carve((size_t)NG * 512 * 2);
    u64*   ring0 = (u64*)carve((size_t)4 * 8 * 2048 * 8);       // 512 KB
    u64*   ring1 = (u64*)carve((size_t)4 * 8 * 2048 * 8);       // 512 KB
    u64*   d0r   = (u64*)carve((size_t)DSLOT * 8 * 2048 * 8);   // 4 MB deep h0 ring
    f16*   h1out = (f16*)carve((size_t)B_ * H_ * 2);

    hipMemsetAsync(ring0, 0, (size_t)4 * 8 * 2048 * 8, stream);
    hipMemsetAsync(ring1, 0, (size_t)4 * 8 * 2048 * 8, stream);
    hipMemsetAsync(d0r, 0, (size_t)DSLOT * 8 * 2048 * 8, stream);

    k_embconv<<<(V_ * E_ / 4 + 255) / 256, 256, 0, stream>>>(emb, embh);
    k_packW<<<384, 256, 0, stream>>>(gw0, 768, 0,    giw0, Wx0, 256);
    k_packW<<<768, 256, 0, stream>>>(gw0, 768, 256,  ghw0, Wh0, 512);
    k_packW<<<768, 256, 0, stream>>>(gw1, 1024, 0,   giw1, Wx1, 512);
    k_packW<<<768, 256, 0, stream>>>(gw1, 1024, 512, ghw1, Wh1, 512);

    k_fused<<<256, 256, 0, stream>>>(Wx0, Wh0, Wx1, Wh1,
                                     gb0, gib0, ghb0, gb1, gib1, ghb1,
                                     tokens, embh, ring0, ring1, d0r, h1out);
    k_final<<<1, 64, 0, stream>>>(h1out, fc_w, fc_b, (float*)d_out);
}